// Round 1
// baseline (160.277 us; speedup 1.0000x reference)
//
#include <hip/hip_runtime.h>

#define NT 32   // nodes per block

typedef __attribute__((ext_vector_type(4))) float f32x4;
typedef __attribute__((ext_vector_type(8))) __bf16 bf16x8;
typedef __attribute__((ext_vector_type(8))) unsigned short u16x8;
typedef __attribute__((ext_vector_type(2))) unsigned int u32x2;

__device__ __forceinline__ unsigned short f2bf(float f) {
    unsigned u = __builtin_bit_cast(unsigned, f);
    u += 0x7fffu + ((u >> 16) & 1u);   // RNE
    return (unsigned short)(u >> 16);
}
__device__ __forceinline__ unsigned pack2(float a, float b) {
    return (unsigned)f2bf(a) | ((unsigned)f2bf(b) << 16);
}

// Pre-arrange B matrices in MFMA-fragment-major order (bf16), weights pre-scaled.
// frag element index: ((sel*8 + kt)*8 + nt)*512 + lane*8 + j
// value = Bsel[k = kt*32 + (lane>>4)*8 + j][w = nt*16 + (lane&15)]
// B0 = [ALPHA*W1 ; ALPHA*INV_SQRT3*W4],  B1 = [ALPHA*W2 ; ALPHA*W3]
__global__ void build_bfrag_kernel(const float* __restrict__ W1,
                                   const float* __restrict__ W2,
                                   const float* __restrict__ W3,
                                   const float* __restrict__ W4,
                                   unsigned short* __restrict__ bfrag) {
    const float ALPHA = 0.0625f;                 // 1/sqrt(2*128)
    const float INV_SQRT3 = 0.57735026918962576f;
    int i = blockIdx.x * 256 + threadIdx.x;      // 0..65535
    int j   = i & 7;
    int l   = (i >> 3) & 63;
    int nt  = (i >> 9) & 7;
    int kt  = (i >> 12) & 7;
    int sel = (i >> 15) & 1;
    int k = kt * 32 + (l >> 4) * 8 + j;
    int w = nt * 16 + (l & 15);
    float v;
    if (sel == 0) {
        v = (k < 128) ? ALPHA * W1[k * 128 + w]
                      : ALPHA * INV_SQRT3 * W4[(k - 128) * 128 + w];
    } else {
        v = (k < 128) ? ALPHA * W2[k * 128 + w]
                      : ALPHA * W3[(k - 128) * 128 + w];
    }
    bfrag[i] = f2bf(v);
}

__global__ __launch_bounds__(256, 2)
void o3tp_kernel(const float* __restrict__ x, const float* __restrict__ y,
                 const float* __restrict__ bias,
                 const unsigned short* __restrict__ bfrag,
                 float* __restrict__ out) {
    // smem: phase 1 = Aeff[4 types][32 rows][256 k] bf16 (XOR-swizzled rows)
    //       phase 3 = C  [4 types][32 rows][128 w] f32   (same 64 KB, per-type slab aliases)
    __shared__ __align__(16) unsigned char smem[65536];
    const int tid = threadIdx.x;
    const int nb  = blockIdx.x * NT;

    // ---------------- producer: build Aeff in LDS ----------------
    {
        const int g  = tid & 31;   // u-group of 4
        const int n0 = tid >> 5;   // 0..7
        #pragma unroll
        for (int pass = 0; pass < 4; ++pass) {
            const int n = n0 + pass * 8;                 // local node 0..31
            const long row = (long)(nb + n) * 512;
            f32x4 X0 = *(const f32x4*)(x + row + 4 * g);
            f32x4 T0 = *(const f32x4*)(x + row + 128 + 12 * g);
            f32x4 T1 = *(const f32x4*)(x + row + 128 + 12 * g + 4);
            f32x4 T2 = *(const f32x4*)(x + row + 128 + 12 * g + 8);
            f32x4 Y  = *(const f32x4*)(y + (long)(nb + n) * 4);
            float y0 = Y[0], ya = Y[1], yb = Y[2], yc = Y[3];
            float e0 = T0[0], e1 = T0[1], e2  = T0[2], e3  = T0[3];
            float e4 = T1[0], e5 = T1[1], e6  = T1[2], e7  = T1[3];
            float e8 = T2[0], e9 = T2[1], e10 = T2[2], e11 = T2[3];
            // s[u] = x1[u,:] . y1
            float s0 = e0 * ya + e1  * yb + e2  * yc;
            float s1 = e3 * ya + e4  * yb + e5  * yc;
            float s2 = e6 * ya + e7  * yb + e8  * yc;
            float s3 = e9 * ya + e10 * yb + e11 * yc;
            const int swz  = (n & 7) << 4;
            const int base = n * 512;
            const int klo  = ((8 * g)       ^ swz) + base;
            const int khi  = ((256 + 8 * g) ^ swz) + base;
            auto WR = [&](int t, int kb, float a, float b2, float c, float d) {
                u32x2 v; v[0] = pack2(a, b2); v[1] = pack2(c, d);
                *(u32x2*)(smem + t * 16384 + kb) = v;
            };
            WR(0, klo, y0 * X0[0], y0 * X0[1], y0 * X0[2], y0 * X0[3]);
            WR(0, khi, s0, s1, s2, s3);
            WR(1, klo, ya * X0[0], ya * X0[1], ya * X0[2], ya * X0[3]);
            WR(1, khi, y0 * e0, y0 * e3, y0 * e6, y0 * e9);
            WR(2, klo, yb * X0[0], yb * X0[1], yb * X0[2], yb * X0[3]);
            WR(2, khi, y0 * e1, y0 * e4, y0 * e7, y0 * e10);
            WR(3, klo, yc * X0[0], yc * X0[1], yc * X0[2], yc * X0[3]);
            WR(3, khi, y0 * e2, y0 * e5, y0 * e8, y0 * e11);
        }
    }
    __syncthreads();

    // ---------------- MFMA: wave t computes C_t (32x128) ----------------
    const int wv   = tid >> 6;     // wave id == output type
    const int l    = tid & 63;
    const int lrow = l & 15;
    const int lk   = l >> 4;

    u16x8 afr[2][8];
    #pragma unroll
    for (int m = 0; m < 2; ++m) {
        #pragma unroll
        for (int kt = 0; kt < 8; ++kt) {
            int r = m * 16 + lrow;
            int kbyte = kt * 64 + lk * 16;
            int addr = wv * 16384 + r * 512 + (kbyte ^ ((r & 7) << 4));
            afr[m][kt] = *(const u16x8*)(smem + addr);
        }
    }

    f32x4 acc[2][8];
    #pragma unroll
    for (int m = 0; m < 2; ++m)
        #pragma unroll
        for (int nt = 0; nt < 8; ++nt) {
            f32x4 z = {0.f, 0.f, 0.f, 0.f};
            acc[m][nt] = z;
        }

    const unsigned short* bbase = bfrag + (wv ? 32768 : 0) + l * 8;
    #pragma unroll
    for (int nt = 0; nt < 8; ++nt) {
        u16x8 bfr[8];
        #pragma unroll
        for (int kt = 0; kt < 8; ++kt)
            bfr[kt] = *(const u16x8*)(bbase + (kt * 8 + nt) * 512);
        #pragma unroll
        for (int kt = 0; kt < 8; ++kt) {
            acc[0][nt] = __builtin_amdgcn_mfma_f32_16x16x32_bf16(
                __builtin_bit_cast(bf16x8, afr[0][kt]),
                __builtin_bit_cast(bf16x8, bfr[kt]), acc[0][nt], 0, 0, 0);
            acc[1][nt] = __builtin_amdgcn_mfma_f32_16x16x32_bf16(
                __builtin_bit_cast(bf16x8, afr[1][kt]),
                __builtin_bit_cast(bf16x8, bfr[kt]), acc[1][nt], 0, 0, 0);
        }
    }

    // bias only on type 0 (added after the ALPHA-scaled sums, as in the reference)
    if (wv == 0) {
        #pragma unroll
        for (int nt = 0; nt < 8; ++nt) {
            float bv = bias[nt * 16 + lrow];
            #pragma unroll
            for (int m = 0; m < 2; ++m)
                #pragma unroll
                for (int j = 0; j < 4; ++j)
                    acc[m][nt][j] += bv;
        }
    }

    // store C_t into own slab (in-wave DS ordering makes this safe, no barrier needed)
    // C/D layout: row(node) = (lane>>4)*4 + reg, col(w) = lane&15   [m89-verified]
    float* cslab = (float*)(smem + wv * 16384);
    #pragma unroll
    for (int m = 0; m < 2; ++m)
        #pragma unroll
        for (int nt = 0; nt < 8; ++nt)
            #pragma unroll
            for (int j = 0; j < 4; ++j)
                cslab[(m * 16 + lk * 4 + j) * 128 + nt * 16 + lrow] = acc[m][nt][j];

    __syncthreads();

    // ---------------- coalesced writeout with w*3+i interleave ----------------
    const float* call = (const float*)smem;   // [type][32][128] f32
    #pragma unroll 4
    for (int it = 0; it < 16; ++it) {
        int idx = it * 256 + tid;    // 0..4095
        int n = idx >> 7;            // local node
        int p = idx & 127;           // float4 position within the 512-float row
        f32x4 v;
        if (p < 32) {
            v = *(const f32x4*)(call + n * 128 + p * 4);          // out0 block
        } else {
            int q = p * 4 - 128;     // flat index into out1 region (= w*3 + i)
            #pragma unroll
            for (int c = 0; c < 4; ++c) {
                int qq = q + c;
                int w  = qq / 3;
                int i3 = qq - w * 3;
                v[c] = call[(1 + i3) * 4096 + n * 128 + w];
            }
        }
        *(f32x4*)(out + (long)(nb + n) * 512 + p * 4) = v;
    }
}

extern "C" void kernel_launch(void* const* d_in, const int* in_sizes, int n_in,
                              void* d_out, int out_size, void* d_ws, size_t ws_size,
                              hipStream_t stream) {
    const float* x  = (const float*)d_in[0];
    const float* y  = (const float*)d_in[1];
    const float* W1 = (const float*)d_in[2];
    const float* W2 = (const float*)d_in[3];
    const float* W3 = (const float*)d_in[4];
    const float* W4 = (const float*)d_in[5];
    const float* b  = (const float*)d_in[6];
    float* out = (float*)d_out;
    unsigned short* bfrag = (unsigned short*)d_ws;   // 65536 bf16 = 128 KB

    int n_nodes = in_sizes[0] / 512;
    hipLaunchKernelGGL(build_bfrag_kernel, dim3(256), dim3(256), 0, stream,
                       W1, W2, W3, W4, bfrag);
    hipLaunchKernelGGL(o3tp_kernel, dim3(n_nodes / NT), dim3(256), 0, stream,
                       x, y, b, bfrag, out);
}